// Round 14
// baseline (5383.746 us; speedup 1.0000x reference)
//
#include <hip/hip_runtime.h>
#include <stdint.h>

// ---------------------------------------------------------------------------
// LIDM forward, round 14: r13 + LDS-STAGED panel loads.
// Each 32KB B-panel (hp/ip/V) is loaded from L3 ONCE per block (coalesced
// sc0/sc1 coop load -> LDS stage buffer), then ds_read by all 8 waves.
// L3 read traffic per beat drops 8x (768KB -> 96KB per block).
// ---------------------------------------------------------------------------
#define S_ 256
#define B_ 64
#define O_ 128
#define L_ 256
#define NL_ 25

typedef __attribute__((ext_vector_type(8))) short short8v;
typedef __attribute__((ext_vector_type(16))) float f32x16;
typedef __attribute__((ext_vector_type(4))) uint32_t u32x4;
typedef __attribute__((ext_vector_type(2))) uint32_t u32x2;

// ---- workspace byte offsets ----
#define EMLP_B  0u           // u16 [256][32][64][8]  (fragment-major)
#define HL_B    8388608u     // u16 e1tmp / Hlast [k][fi][b]
#define Z0P_B   16777216u    // u16 [25][32][64][8]
#define RING_B  17596416u    // u16 [25][8][32][64][8]
#define VBUF_B  24150016u    // u16 [25][16][32][64][8]
#define WF_B    37257216u    // u16 [25][1024][256]
#define WN_B    50364416u    // u16 [25][8][32768]
#define BIASF_B 63471616u    // f32 [25][1024]
#define FLAG_B  63574016u    // u64 per layer @ 256B stride
#define NFLAG_B 63580416u    // u16 per (l, p&15) @ 64B stride
#define WS_END  63626016u

#define VMWAIT                                                                   \
  do {                                                                           \
    asm volatile("s_waitcnt vmcnt(0)" ::: "memory");                             \
    __builtin_amdgcn_sched_barrier(0);                                           \
  } while (0)

#define GST16(PTR, VAL)                                                          \
  do {                                                                           \
    uint64_t a_ = (uint64_t)(uintptr_t)(PTR);                                    \
    asm volatile("global_store_dwordx4 %0, %1, off sc0 sc1" :: "v"(a_), "v"(VAL) : "memory"); \
  } while (0)

#define GST8(PTR, VAL)                                                           \
  do {                                                                           \
    uint64_t a_ = (uint64_t)(uintptr_t)(PTR);                                    \
    asm volatile("global_store_dwordx2 %0, %1, off sc0 sc1" :: "v"(a_), "v"(VAL) : "memory"); \
  } while (0)

#define VMDRAIN asm volatile("s_waitcnt vmcnt(0)" ::: "memory")

// cooperative 32KB panel load: thread t loads 4x16B (coalesced, sc-bypass)
#define PANEL_LD(R0, R1, R2, R3, BASE)                                           \
  do {                                                                           \
    uint64_t a0_ = (uint64_t)(uintptr_t)(BASE) + (uint32_t)(t * 16);             \
    uint64_t a1_ = a0_ + 8192, a2_ = a0_ + 16384, a3_ = a0_ + 24576;             \
    asm volatile("global_load_dwordx4 %0, %1, off sc0 sc1" : "=v"(R0) : "v"(a0_)); \
    asm volatile("global_load_dwordx4 %0, %1, off sc0 sc1" : "=v"(R1) : "v"(a1_)); \
    asm volatile("global_load_dwordx4 %0, %1, off sc0 sc1" : "=v"(R2) : "v"(a2_)); \
    asm volatile("global_load_dwordx4 %0, %1, off sc0 sc1" : "=v"(R3) : "v"(a3_)); \
  } while (0)

#define PANEL_ST(R0, R1, R2, R3)                                                 \
  do {                                                                           \
    *reinterpret_cast<u32x4*>(ST + t * 16)         = R0;                         \
    *reinterpret_cast<u32x4*>(ST + 8192 + t * 16)  = R1;                         \
    *reinterpret_cast<u32x4*>(ST + 16384 + t * 16) = R2;                         \
    *reinterpret_cast<u32x4*>(ST + 24576 + t * 16) = R3;                         \
  } while (0)

#define PANEL_RD(BV)                                                             \
  do {                                                                           \
    _Pragma("unroll")                                                            \
    for (int kt_ = 0; kt_ < 16; ++kt_)                                           \
      BV[kt_] = *reinterpret_cast<const short8v*>(ST + kt_ * 2048 + blane);      \
  } while (0)

// full staged fetch: (caller ensures uniform control flow)
#define STAGE_PANEL(BV, GBASE)                                                   \
  do {                                                                           \
    u32x4 r0_, r1_, r2_, r3_;                                                    \
    PANEL_LD(r0_, r1_, r2_, r3_, GBASE);                                         \
    VMWAIT;                                                                      \
    __syncthreads();                                                             \
    PANEL_ST(r0_, r1_, r2_, r3_);                                                \
    __syncthreads();                                                             \
    PANEL_RD(BV);                                                                \
  } while (0)

// ---------------------------- helpers --------------------------------------
__device__ __forceinline__ uint16_t f2bf(float x) {
  uint32_t u = __float_as_uint(x);
  return (uint16_t)((u + 0x7fffu + ((u >> 16) & 1u)) >> 16);
}
__device__ __forceinline__ float bf2f(uint16_t u) {
  return __uint_as_float(((uint32_t)u) << 16);
}
__device__ __forceinline__ short8v pack8(float4 a, float4 b) {
  short8v w;
  w[0] = (short)f2bf(a.x); w[1] = (short)f2bf(a.y);
  w[2] = (short)f2bf(a.z); w[3] = (short)f2bf(a.w);
  w[4] = (short)f2bf(b.x); w[5] = (short)f2bf(b.y);
  w[6] = (short)f2bf(b.z); w[7] = (short)f2bf(b.w);
  return w;
}

__device__ __forceinline__ uint32_t rotl32(uint32_t v, int r) {
  return (v << r) | (v >> (32 - r));
}

__device__ __forceinline__ void tf2x32(uint32_t k0, uint32_t k1,
                                       uint32_t x0, uint32_t x1,
                                       uint32_t& o0, uint32_t& o1) {
  uint32_t ks2 = k0 ^ k1 ^ 0x1BD11BDAu;
  x0 += k0; x1 += k1;
  x0 += x1; x1 = rotl32(x1, 13); x1 ^= x0;
  x0 += x1; x1 = rotl32(x1, 15); x1 ^= x0;
  x0 += x1; x1 = rotl32(x1, 26); x1 ^= x0;
  x0 += x1; x1 = rotl32(x1,  6); x1 ^= x0;
  x0 += k1; x1 += ks2 + 1u;
  x0 += x1; x1 = rotl32(x1, 17); x1 ^= x0;
  x0 += x1; x1 = rotl32(x1, 29); x1 ^= x0;
  x0 += x1; x1 = rotl32(x1, 16); x1 ^= x0;
  x0 += x1; x1 = rotl32(x1, 24); x1 ^= x0;
  x0 += ks2; x1 += k0 + 2u;
  x0 += x1; x1 = rotl32(x1, 13); x1 ^= x0;
  x0 += x1; x1 = rotl32(x1, 15); x1 ^= x0;
  x0 += x1; x1 = rotl32(x1, 26); x1 ^= x0;
  x0 += x1; x1 = rotl32(x1,  6); x1 ^= x0;
  x0 += k0; x1 += k1 + 3u;
  x0 += x1; x1 = rotl32(x1, 17); x1 ^= x0;
  x0 += x1; x1 = rotl32(x1, 29); x1 ^= x0;
  x0 += x1; x1 = rotl32(x1, 16); x1 ^= x0;
  x0 += x1; x1 = rotl32(x1, 24); x1 ^= x0;
  x0 += k1; x1 += ks2 + 4u;
  x0 += x1; x1 = rotl32(x1, 13); x1 ^= x0;
  x0 += x1; x1 = rotl32(x1, 15); x1 ^= x0;
  x0 += x1; x1 = rotl32(x1, 26); x1 ^= x0;
  x0 += x1; x1 = rotl32(x1,  6); x1 ^= x0;
  o0 = x0 + ks2; o1 = x1 + k0 + 5u;
}

__device__ __forceinline__ void step_keys(int k, uint32_t& kh0, uint32_t& kh1,
                                          uint32_t& kx0, uint32_t& kx1) {
  uint32_t f0, f1;
  tf2x32(0u, 42u, 0u, (uint32_t)k, f0, f1);
  tf2x32(f0, f1, 0u, 0u, kh0, kh1);
  tf2x32(f0, f1, 0u, 1u, kx0, kx1);
}

__device__ __forceinline__ uint32_t rbits(uint32_t key0, uint32_t key1,
                                          uint32_t i) {
  uint32_t b0, b1;
  tf2x32(key0, key1, 0u, i, b0, b1);
  return b0 ^ b1;
}

__device__ __forceinline__ float u32_to_normal(uint32_t bits) {
  const float lo = __uint_as_float(0xBF7FFFFFu);
  float f = __uint_as_float((bits >> 9) | 0x3F800000u) - 1.0f;
  float u = f * 2.0f + lo;
  u = fmaxf(lo, u);
  float x = u;
  float w = -log1pf(-x * x);
  float p;
  if (w < 5.0f) {
    w -= 2.5f;
    p =            2.81022636e-08f;
    p = fmaf(p, w, 3.43273939e-07f);
    p = fmaf(p, w, -3.5233877e-06f);
    p = fmaf(p, w, -4.39150654e-06f);
    p = fmaf(p, w, 0.00021858087f);
    p = fmaf(p, w, -0.00125372503f);
    p = fmaf(p, w, -0.00417768164f);
    p = fmaf(p, w, 0.246640727f);
    p = fmaf(p, w, 1.50140941f);
  } else {
    w = sqrtf(w) - 3.0f;
    p =            -0.000200214257f;
    p = fmaf(p, w, 0.000100950558f);
    p = fmaf(p, w, 0.00134934322f);
    p = fmaf(p, w, -0.00367342844f);
    p = fmaf(p, w, 0.00573950773f);
    p = fmaf(p, w, -0.0076224613f);
    p = fmaf(p, w, 0.00943887047f);
    p = fmaf(p, w, 1.00167406f);
    p = fmaf(p, w, 2.83297682f);
  }
  return __uint_as_float(0x3FB504F3u) * (p * x);
}

__device__ __forceinline__ float sigm(float x) { return 1.0f / (1.0f + expf(-x)); }

// ---- flag primitives ----
__device__ __forceinline__ uint64_t ld_u64_sc(const uint64_t* p) {
  uint64_t v;
  asm volatile("global_load_dwordx2 %0, %1, off sc0 sc1\n\ts_waitcnt vmcnt(0)"
               : "=v"(v) : "v"((uint64_t)(uintptr_t)p) : "memory");
  return v;
}
__device__ __forceinline__ uint32_t ld_u16_sc(const uint16_t* p) {
  uint32_t v;
  asm volatile("global_load_ushort %0, %1, off sc0 sc1\n\ts_waitcnt vmcnt(0)"
               : "=v"(v) : "v"((uint64_t)(uintptr_t)p) : "memory");
  return v;
}
__device__ __forceinline__ void spin_bytes_ge(const uint64_t* p, uint32_t want) {
  for (;;) {
    uint64_t v = ld_u64_sc(p);
    bool ok = true;
#pragma unroll
    for (int i = 0; i < 8; ++i) ok &= (uint32_t)((v >> (8 * i)) & 0xffu) >= want;
    if (ok) return;
    __builtin_amdgcn_s_sleep(4);
  }
}
__device__ __forceinline__ void spin_nf(const uint16_t* p, uint32_t pid) {
  uint32_t want = (pid & 0xffu) | ((pid & 0xffu) << 8);
  while (ld_u16_sc(p) != want) __builtin_amdgcn_s_sleep(4);
}
__device__ __forceinline__ void st_u8_sc(uint8_t* p, uint32_t v) {
  asm volatile("global_store_byte %0, %1, off sc0 sc1"
               :: "v"((uint64_t)(uintptr_t)p), "v"(v) : "memory");
}

// quarter-panel noise generator (fragment-major vbuf)
__device__ __forceinline__ void gen_quarter(uint16_t* __restrict__ vbl,
                                            int l, int p, int s, int t, int q) {
  uint32_t kh0, kh1, kx0, kx1;
  step_keys(p, kh0, kh1, kx0, kx1);
  int vb = 32 * (s & 1) + (t >> 4);
  int fs = (t & 15) * 16 + q * 4;
  uint32_t ib = ((uint32_t)(l * 64 + vb)) * 256 + (uint32_t)fs;
  int g = fs >> 3;
  uint16_t* dst = vbl + (((size_t)(p & 15)) << 14) + ((size_t)(g * 64 + vb)) * 8 + (fs & 7);
  uint16_t n0 = f2bf(0.1f * u32_to_normal(rbits(kh0, kh1, ib + 0)));
  uint16_t n1 = f2bf(0.1f * u32_to_normal(rbits(kh0, kh1, ib + 1)));
  uint16_t n2 = f2bf(0.1f * u32_to_normal(rbits(kh0, kh1, ib + 2)));
  uint16_t n3 = f2bf(0.1f * u32_to_normal(rbits(kh0, kh1, ib + 3)));
  u32x2 dv;
  dv[0] = (uint32_t)n0 | ((uint32_t)n1 << 16);
  dv[1] = (uint32_t)n2 | ((uint32_t)n3 << 16);
  GST8(dst, dv);
}

// ------------------------------- prep kernels ------------------------------
__global__ __launch_bounds__(256) void k_init(const float* __restrict__ z0,
                                              uint16_t* __restrict__ z0p,
                                              uint32_t* __restrict__ fl) {
  int idx = blockIdx.x * 256 + threadIdx.x;
  int fi = idx & 255;
  int b = (idx >> 8) & 63;
  int l = idx >> 14;
  z0p[(((size_t)l * 32 + (fi >> 3)) * 64 + b) * 8 + (fi & 7)] = f2bf(z0[idx]);
  if (idx < 8000) fl[idx] = 0u;
}

__global__ __launch_bounds__(256) void k_wf(const float* __restrict__ Whh,
                                            const float* __restrict__ Wemb,
                                            uint16_t* __restrict__ Wf) {
  __shared__ float Bs[32][256];
  int l = blockIdx.x >> 4, rt = blockIdx.x & 15;
  int j = threadIdx.x;
  float acc[64];
#pragma unroll
  for (int r = 0; r < 64; ++r) acc[r] = 0.0f;
  const float* Abase = Whh + ((size_t)l * 1024 + rt * 64) * 256;
  for (int m0 = 0; m0 < 256; m0 += 32) {
    __syncthreads();
    {
      int rr = threadIdx.x >> 3, cseg = threadIdx.x & 7;
      const float* src = Wemb + (size_t)(m0 + rr) * 256 + cseg * 32;
      float* dst = &Bs[rr][cseg * 32];
#pragma unroll
      for (int q = 0; q < 8; ++q)
        reinterpret_cast<float4*>(dst)[q] = reinterpret_cast<const float4*>(src)[q];
    }
    __syncthreads();
    for (int mm = 0; mm < 32; ++mm) {
      float bj = Bs[mm][j];
      const float* Acol = Abase + m0 + mm;
#pragma unroll
      for (int r = 0; r < 64; ++r) acc[r] = fmaf(Acol[r * 256], bj, acc[r]);
    }
  }
  for (int r = 0; r < 64; ++r)
    Wf[((size_t)l * 1024 + rt * 64 + r) * 256 + j] = f2bf(acc[r]);
}

__global__ __launch_bounds__(256) void k_wn(const float* __restrict__ Whh,
                                            uint16_t* __restrict__ Wn) {
  int l = blockIdx.x >> 3, s = blockIdx.x & 7;
  uint16_t* base = Wn + ((size_t)(l * 8 + s) << 15);
  for (int it = 0; it < 16; ++it) {
    int c = it * 256 + threadIdx.x;
    int c2 = c >> 7;
    int r = c & 127;
    int gi = (r & 3) * 256 + s * 32 + (r >> 5) * 8 + ((r >> 2) & 7);
    const float* src = Whh + ((size_t)l * 1024 + gi) * 256 + c2 * 8;
    float4 f0 = *reinterpret_cast<const float4*>(src);
    float4 f1 = *reinterpret_cast<const float4*>(src + 4);
    *reinterpret_cast<short8v*>(base + (size_t)c * 8) = pack8(f0, f1);
  }
}

__global__ __launch_bounds__(256) void k_biasf(const float* __restrict__ Whh,
                                               const float* __restrict__ bemb,
                                               const float* __restrict__ bih,
                                               const float* __restrict__ bhh,
                                               float* __restrict__ biasf) {
  int l = blockIdx.x >> 2;
  int gi = (blockIdx.x & 3) * 256 + threadIdx.x;
  const float* row = Whh + ((size_t)l * 1024 + gi) * 256;
  float a = 0.0f;
  for (int m = 0; m < 256; ++m) a = fmaf(row[m], bemb[m], a);
  biasf[l * 1024 + gi] = a + bih[l * 1024 + gi] + bhh[l * 1024 + gi];
}

__global__ __launch_bounds__(256) void k_mlp1(const float* __restrict__ obsrv,
                                              const float* __restrict__ Wx1,
                                              const float* __restrict__ bx1,
                                              uint16_t* __restrict__ e1out) {
  int k = 1 + (blockIdx.x >> 2);
  int jc = blockIdx.x & 3;
  int lane = threadIdx.x & 63;
  int wv = threadIdx.x >> 6;
  int j0 = jc * 64 + wv * 16;
  const float* xrow = obsrv + ((size_t)k * B_ + lane) * O_;
  float acc[16];
#pragma unroll
  for (int i = 0; i < 16; ++i) acc[i] = 0.0f;
  for (int o = 0; o < O_; o += 4) {
    float4 a = *reinterpret_cast<const float4*>(&xrow[o]);
#pragma unroll
    for (int mi = 0; mi < 16; ++mi) {
      float4 wt = *reinterpret_cast<const float4*>(&Wx1[(size_t)(j0 + mi) * O_ + o]);
      float t = acc[mi];
      t = fmaf(a.x, wt.x, t); t = fmaf(a.y, wt.y, t);
      t = fmaf(a.z, wt.z, t); t = fmaf(a.w, wt.w, t);
      acc[mi] = t;
    }
  }
  uint16_t* dst = e1out + (size_t)k * L_ * B_;
#pragma unroll
  for (int mi = 0; mi < 16; ++mi) {
    float v = acc[mi] + bx1[j0 + mi];
    dst[(j0 + mi) * B_ + lane] = f2bf(fmaxf(v, 0.0f));
  }
}

// E_mlp fragment-major: [k][fi>>3][b][fi&7]
__global__ __launch_bounds__(256) void k_mlp2(const uint16_t* __restrict__ e1buf,
                                              const float* __restrict__ Wx2,
                                              const float* __restrict__ bx2,
                                              const float* __restrict__ Wx3,
                                              const float* __restrict__ bx3,
                                              uint16_t* __restrict__ E_mlp) {
  __shared__ float e2s[L_ * B_];
  int k = 1 + blockIdx.x;
  int lane = threadIdx.x & 63;
  int wv = threadIdx.x >> 6;
  const uint16_t* e1 = e1buf + (size_t)k * L_ * B_;

  for (int rep = 0; rep < 4; ++rep) {
    int m0 = rep * 64 + wv * 16;
    float acc[16];
#pragma unroll
    for (int i = 0; i < 16; ++i) acc[i] = 0.0f;
    for (int j = 0; j < L_; j += 4) {
      float a0 = bf2f(e1[(j + 0) * B_ + lane]);
      float a1 = bf2f(e1[(j + 1) * B_ + lane]);
      float a2 = bf2f(e1[(j + 2) * B_ + lane]);
      float a3 = bf2f(e1[(j + 3) * B_ + lane]);
#pragma unroll
      for (int mi = 0; mi < 16; ++mi) {
        float4 wt = *reinterpret_cast<const float4*>(&Wx2[(size_t)(m0 + mi) * L_ + j]);
        float t = acc[mi];
        t = fmaf(a0, wt.x, t); t = fmaf(a1, wt.y, t);
        t = fmaf(a2, wt.z, t); t = fmaf(a3, wt.w, t);
        acc[mi] = t;
      }
    }
#pragma unroll
    for (int mi = 0; mi < 16; ++mi) {
      float v = acc[mi] + bx2[m0 + mi];
      e2s[(m0 + mi) * B_ + lane] = fmaxf(v, 0.0f);
    }
  }
  __syncthreads();

  uint32_t kh0, kh1, kx0, kx1;
  step_keys(k, kh0, kh1, kx0, kx1);
  const float sa = sqrtf(0.9f);

  for (int rep = 0; rep < 4; ++rep) {
    int m0 = rep * 64 + wv * 16;
    float acc[16];
#pragma unroll
    for (int i = 0; i < 16; ++i) acc[i] = 0.0f;
    for (int j = 0; j < L_; j += 4) {
      float a0 = e2s[(j + 0) * B_ + lane];
      float a1 = e2s[(j + 1) * B_ + lane];
      float a2 = e2s[(j + 2) * B_ + lane];
      float a3 = e2s[(j + 3) * B_ + lane];
#pragma unroll
      for (int mi = 0; mi < 16; ++mi) {
        float4 wt = *reinterpret_cast<const float4*>(&Wx3[(size_t)(m0 + mi) * L_ + j]);
        float t = acc[mi];
        t = fmaf(a0, wt.x, t); t = fmaf(a1, wt.y, t);
        t = fmaf(a2, wt.z, t); t = fmaf(a3, wt.w, t);
        acc[mi] = t;
      }
    }
    uint16_t tmp[16];
#pragma unroll
    for (int mi = 0; mi < 16; ++mi) {
      int m = m0 + mi;
      float nz = u32_to_normal(rbits(kx0, kx1, (uint32_t)(lane * L_ + m)));
      tmp[mi] = f2bf(sa * (acc[mi] + bx3[m]) + 0.1f * nz);
    }
    int g0 = m0 >> 3;
    uint16_t* d0 = E_mlp + (((size_t)k * 32 + g0) * 64 + lane) * 8;
    uint16_t* d1 = E_mlp + (((size_t)k * 32 + g0 + 1) * 64 + lane) * 8;
    *reinterpret_cast<uint4*>(d0) = *reinterpret_cast<const uint4*>(&tmp[0]);
    *reinterpret_cast<uint4*>(d1) = *reinterpret_cast<const uint4*>(&tmp[8]);
  }
}

// ------------------------------ wavefront ----------------------------------
__global__ __launch_bounds__(512, 1) void k_wave(
    const uint16_t* __restrict__ Wf, const float* __restrict__ W_ih,
    const uint16_t* __restrict__ Wn, const float* __restrict__ biasf,
    const uint16_t* __restrict__ z0p, const uint16_t* __restrict__ emlp,
    uint16_t* __restrict__ ring, uint16_t* __restrict__ vbuf,
    uint16_t* __restrict__ hlast, uint8_t* __restrict__ flagb,
    uint8_t* __restrict__ nfb) {
  __shared__ __align__(16) unsigned char SMEM[163840];
  unsigned char* WAF = SMEM;            // 65536
  unsigned char* WAI = SMEM + 65536;    // 65536
  unsigned char* ST  = SMEM + 131072;   // 32768 panel stage

  const int slot = (blockIdx.x & 7) * 25 + (blockIdx.x >> 3);
  const int l = slot >> 3;
  const int s = slot & 7;
  const int t = threadIdx.x;
  const int lane = t & 63;
  const int wid = t >> 6;
  const int lo5 = lane & 31;
  const int hi = lane >> 5;
  const int tm = wid >> 1;
  const int tn = wid & 1;
  const int bcol = tn * 32 + lo5;
  const int arow = tm * 32 + lo5;
  const int aswz = (arow & 7) << 4;

#pragma unroll 1
  for (int it = 0; it < 8; ++it) {
    int c = it * 512 + t;
    int r = c >> 5, cc = c & 31;
    int gi = (r & 3) * 256 + s * 32 + (r >> 5) * 8 + ((r >> 2) & 7);
    uint4 v = *reinterpret_cast<const uint4*>(Wf + ((size_t)l * 1024 + gi) * 256 + cc * 8);
    *reinterpret_cast<uint4*>(WAF + r * 512 + ((cc * 16) ^ ((r & 7) << 4))) = v;
  }
#pragma unroll 1
  for (int it = 0; it < 8; ++it) {
    int c = it * 512 + t;
    int r = c >> 5, cc = c & 31;
    int gi = (r & 3) * 256 + s * 32 + (r >> 5) * 8 + ((r >> 2) & 7);
    const float* sr = W_ih + ((size_t)l * 1024 + gi) * 256 + cc * 8;
    float4 f0 = *reinterpret_cast<const float4*>(sr);
    float4 f1 = *reinterpret_cast<const float4*>(sr + 4);
    *reinterpret_cast<short8v*>(WAI + r * 512 + ((cc * 16) ^ ((r & 7) << 4))) = pack8(f0, f1);
  }

  float bfr[16];
#pragma unroll
  for (int mq = 0; mq < 4; ++mq) {
    int mi = s * 32 + tm * 8 + mq * 2 + hi;
#pragma unroll
    for (int g = 0; g < 4; ++g)
      bfr[mq * 4 + g] = biasf[l * 1024 + g * 256 + mi];
  }
  __syncthreads();

  uint16_t* vbl = vbuf + ((size_t)(l * 16) << 14);
  const uint16_t* wb = Wn + ((size_t)(l * 8 + s) << 15);
  const int blane = hi * 1024 + bcol * 16;   // fragment-major lane byte offset
  const int ggrp = s * 4 + tm;               // producer fragment group

#define NFE(P) ((uint16_t*)(nfb + ((size_t)(l * 16 + ((P) & 15))) * 64))

  // ---- prologue: generate noise panels 1..8 ----
#pragma unroll 1
  for (int g = 0; g < 2; ++g) {
    int p = 1 + g * 4 + (s >> 1);
#pragma unroll 1
    for (int q = 0; q < 4; ++q) gen_quarter(vbl, l, p, s, t, q);
    VMDRAIN;
    __syncthreads();
    if (t == 0) st_u8_sc((uint8_t*)NFE(p) + (s & 1), (uint32_t)(p & 0xff));
  }

  f32x16 nbt[4];
  float cst[4] = {0.0f, 0.0f, 0.0f, 0.0f};

  // ---- prologue: nbt for steps 1..4 (staged) ----
#pragma unroll 1
  for (int st = 1; st <= 4; ++st) {
    if (t == 0) spin_nf(NFE(st), (uint32_t)st);
    short8v bv[16];
    STAGE_PANEL(bv, (const unsigned char*)vbl + (((size_t)(st & 15)) << 15));
    f32x16 nw = {0,0,0,0,0,0,0,0,0,0,0,0,0,0,0,0};
#pragma unroll
    for (int kt = 0; kt < 16; ++kt) {
      short8v av = *reinterpret_cast<const short8v*>(
          wb + ((size_t)((kt * 2 + hi) * 128 + arow)) * 8);
      nw = __builtin_amdgcn_mfma_f32_32x32x16_bf16(av, bv[kt], nw, 0, 0, 0);
    }
    if (st == 1) nbt[0] = nw;
    else if (st == 2) nbt[1] = nw;
    else if (st == 3) nbt[2] = nw;
    else nbt[3] = nw;
  }

#pragma unroll 1
  for (int k = 1; k <= 255; ++k) {
    // ---- phase 1: sibling flag (k-1) + downstream ring guard (k-8) ----
    if (t == 0 && k > 1) spin_bytes_ge((const uint64_t*)(flagb + l * 256), (uint32_t)(k - 1));
    if (t == 64 && l < NL_ - 1 && k >= 9)
      spin_bytes_ge((const uint64_t*)(flagb + (l + 1) * 256), (uint32_t)(k - 8));
    __syncthreads();

    // ---- hp panel coop load (ready per phase 1) ----
    const unsigned char* hp = (k == 1)
        ? ((const unsigned char*)z0p + (((size_t)l) << 15))
        : ((const unsigned char*)ring + (((size_t)(l * 8 + ((k - 1) & 7))) << 15));
    u32x4 h0, h1, h2, h3;
    PANEL_LD(h0, h1, h2, h3, hp);

    // ---- phase 2: upstream flag (k), overlaps hp load ----
    if (t == 0 && l > 0) spin_bytes_ge((const uint64_t*)(flagb + (l - 1) * 256), (uint32_t)k);
    VMWAIT;
    __syncthreads();       // spin done + previous ST readers drained
    PANEL_ST(h0, h1, h2, h3);
    __syncthreads();

    short8v bv0[16];
    PANEL_RD(bv0);

    // ---- ip panel coop load (in flight during hp MFMAs) ----
    const unsigned char* ip = (l == 0)
        ? ((const unsigned char*)emlp + (((size_t)k) << 15))
        : ((const unsigned char*)ring + (((size_t)((l - 1) * 8 + (k & 7))) << 15));
    u32x4 i0, i1, i2, i3;
    PANEL_LD(i0, i1, i2, i3, ip);

    f32x16 acc = nbt[0];
#pragma unroll
    for (int kt = 0; kt < 16; ++kt) {
      short8v av = *reinterpret_cast<const short8v*>(WAF + arow * 512 + ((kt * 32 + hi * 16) ^ aswz));
      acc = __builtin_amdgcn_mfma_f32_32x32x16_bf16(av, bv0[kt], acc, 0, 0, 0);
    }
    VMWAIT;
    __syncthreads();       // bv0 reads drained
    PANEL_ST(i0, i1, i2, i3);
    __syncthreads();

    short8v bv1[16];
    PANEL_RD(bv1);
#pragma unroll
    for (int kt = 0; kt < 16; ++kt) {
      short8v av = *reinterpret_cast<const short8v*>(WAI + arow * 512 + ((kt * 32 + hi * 16) ^ aswz));
      acc = __builtin_amdgcn_mfma_f32_32x32x16_bf16(av, bv1[kt], acc, 0, 0, 0);
    }

    // ---- LSTM epilogue ----
    uint16_t hv[4];
#pragma unroll
    for (int mq = 0; mq < 4; ++mq) {
      float iv = acc[4 * mq + 0] + bfr[mq * 4 + 0];
      float fv = acc[4 * mq + 1] + bfr[mq * 4 + 1];
      float gv = acc[4 * mq + 2] + bfr[mq * 4 + 2];
      float ov = acc[4 * mq + 3] + bfr[mq * 4 + 3];
      float cn = sigm(fv) * cst[mq] + sigm(iv) * tanhf(gv);
      float hn = sigm(ov) * tanhf(cn);
      cst[mq] = cn;
      hv[mq] = f2bf(hn);
      if (l == NL_ - 1) {
        int mi = s * 32 + tm * 8 + mq * 2 + hi;
        hlast[((size_t)k << 14) + mi * 64 + bcol] = hv[mq];
      }
    }
    {
      uint32_t w0 = (uint32_t)hv[0] | ((uint32_t)hv[1] << 16);
      uint32_t w1 = (uint32_t)hv[2] | ((uint32_t)hv[3] << 16);
      uint32_t p0 = (uint32_t)__shfl_xor((int)w0, 32);
      uint32_t p1 = (uint32_t)__shfl_xor((int)w1, 32);
      if (hi == 0) {
        u32x4 dv;
        dv[0] = (w0 & 0xffffu) | (p0 << 16);
        dv[1] = (w0 >> 16) | (p0 & 0xffff0000u);
        dv[2] = (w1 & 0xffffu) | (p1 << 16);
        dv[3] = (w1 >> 16) | (p1 & 0xffff0000u);
        unsigned char* rp = (unsigned char*)ring +
            (((size_t)(l * 8 + (k & 7))) << 15) + ((size_t)(ggrp * 64 + bcol)) * 16;
        GST16(rp, dv);
      }
    }
    VMDRAIN;
    __syncthreads();
    if (t == 0) st_u8_sc(flagb + l * 256 + s, (uint32_t)(k & 0xff));

    // ================= deferred (off critical path) =================
    {
      int base = ((k - 1) & ~3) + 1;
      int q = (k - 1) & 3;
      int p = base + 8 + (s >> 1);
      if (p <= 255) {
        gen_quarter(vbl, l, p, s, t, q);
        if (q == 3) {
          VMDRAIN;
          __syncthreads();
          if (t == 0) st_u8_sc((uint8_t*)NFE(p) + (s & 1), (uint32_t)(p & 0xff));
        }
      }
    }
    {
      int kn = k + 4;
      f32x16 nw = {0,0,0,0,0,0,0,0,0,0,0,0,0,0,0,0};
      if (kn <= 255) {
        if (t == 0) spin_nf(NFE(kn), (uint32_t)kn);
        short8v bv[16];
        STAGE_PANEL(bv, (const unsigned char*)vbl + (((size_t)(kn & 15)) << 15));
#pragma unroll
        for (int kt = 0; kt < 16; ++kt) {
          short8v av = *reinterpret_cast<const short8v*>(
              wb + ((size_t)((kt * 2 + hi) * 128 + arow)) * 8);
          nw = __builtin_amdgcn_mfma_f32_32x32x16_bf16(av, bv[kt], nw, 0, 0, 0);
        }
      }
      nbt[0] = nbt[1]; nbt[1] = nbt[2]; nbt[2] = nbt[3]; nbt[3] = nw;
    }
  }
#undef NFE
}

// out[k][b][m] = Hlast[k] @ W_out^T + b_out ; out[0] = 0
__global__ __launch_bounds__(256) void k_final(const uint16_t* __restrict__ Hlast,
                                               const float* __restrict__ W_out,
                                               const float* __restrict__ b_out,
                                               float* __restrict__ out) {
  int k = blockIdx.x >> 2;
  int mc = blockIdx.x & 3;
  int lane = threadIdx.x & 63;
  int wv = threadIdx.x >> 6;
  int m0 = mc * 64 + wv * 16;
  float res[16];
  if (k == 0) {
#pragma unroll
    for (int mi = 0; mi < 16; ++mi) res[mi] = 0.0f;
  } else {
    float acc[16];
#pragma unroll
    for (int i = 0; i < 16; ++i) acc[i] = 0.0f;
    const uint16_t* src = Hlast + ((size_t)k << 14);
    for (int j = 0; j < L_; j += 4) {
      float a0 = bf2f(src[(j + 0) * B_ + lane]);
      float a1 = bf2f(src[(j + 1) * B_ + lane]);
      float a2 = bf2f(src[(j + 2) * B_ + lane]);
      float a3 = bf2f(src[(j + 3) * B_ + lane]);
#pragma unroll
      for (int mi = 0; mi < 16; ++mi) {
        float4 wt = *reinterpret_cast<const float4*>(&W_out[(size_t)(m0 + mi) * L_ + j]);
        float t = acc[mi];
        t = fmaf(a0, wt.x, t); t = fmaf(a1, wt.y, t);
        t = fmaf(a2, wt.z, t); t = fmaf(a3, wt.w, t);
        acc[mi] = t;
      }
    }
#pragma unroll
    for (int mi = 0; mi < 16; ++mi) res[mi] = acc[mi] + b_out[m0 + mi];
  }
  float* dst = out + ((size_t)k * B_ + lane) * L_ + m0;
#pragma unroll
  for (int v = 0; v < 4; ++v) {
    float4 t4 = make_float4(res[4 * v], res[4 * v + 1], res[4 * v + 2], res[4 * v + 3]);
    *reinterpret_cast<float4*>(&dst[4 * v]) = t4;
  }
}

// ------------------------------ launcher -----------------------------------
extern "C" void kernel_launch(void* const* d_in, const int* in_sizes, int n_in,
                              void* d_out, int out_size, void* d_ws, size_t ws_size,
                              hipStream_t stream) {
  const float* obsrv = (const float*)d_in[0];
  const float* z0    = (const float*)d_in[1];
  const float* W_emb = (const float*)d_in[2];
  const float* b_emb = (const float*)d_in[3];
  const float* Wx1   = (const float*)d_in[4];
  const float* bx1   = (const float*)d_in[5];
  const float* Wx2   = (const float*)d_in[6];
  const float* bx2   = (const float*)d_in[7];
  const float* Wx3   = (const float*)d_in[8];
  const float* bx3   = (const float*)d_in[9];
  const float* W_ih  = (const float*)d_in[10];
  const float* W_hh  = (const float*)d_in[11];
  const float* b_ih  = (const float*)d_in[12];
  const float* b_hh  = (const float*)d_in[13];
  const float* W_out = (const float*)d_in[14];
  const float* b_out = (const float*)d_in[15];
  float* out = (float*)d_out;
  unsigned char* ws = (unsigned char*)d_ws;

  if (ws_size < (size_t)WS_END) return;

  uint16_t* E_mlp = (uint16_t*)(ws + EMLP_B);
  uint16_t* e1tmp = (uint16_t*)(ws + HL_B);
  uint16_t* Hlast = (uint16_t*)(ws + HL_B);
  uint16_t* z0p   = (uint16_t*)(ws + Z0P_B);
  uint16_t* ring  = (uint16_t*)(ws + RING_B);
  uint16_t* vbuf  = (uint16_t*)(ws + VBUF_B);
  uint16_t* Wf    = (uint16_t*)(ws + WF_B);
  uint16_t* Wn    = (uint16_t*)(ws + WN_B);
  float*    biasf = (float*)(ws + BIASF_B);
  uint8_t*  flagb = (uint8_t*)(ws + FLAG_B);
  uint8_t*  nfb   = (uint8_t*)(ws + NFLAG_B);

  k_init<<<1600, 256, 0, stream>>>(z0, z0p, (uint32_t*)(ws + FLAG_B));
  k_wf<<<25 * 16, 256, 0, stream>>>(W_hh, W_emb, Wf);
  k_wn<<<25 * 8, 256, 0, stream>>>(W_hh, Wn);
  k_biasf<<<25 * 4, 256, 0, stream>>>(W_hh, b_emb, b_ih, b_hh, biasf);
  k_mlp1<<<255 * 4, 256, 0, stream>>>(obsrv, Wx1, bx1, e1tmp);
  k_mlp2<<<255, 256, 0, stream>>>(e1tmp, Wx2, bx2, Wx3, bx3, E_mlp);

  void* args[] = {(void*)&Wf, (void*)&W_ih, (void*)&Wn, (void*)&biasf,
                  (void*)&z0p, (void*)&E_mlp, (void*)&ring, (void*)&vbuf,
                  (void*)&Hlast, (void*)&flagb, (void*)&nfb};
  hipLaunchCooperativeKernel((const void*)k_wave, dim3(NL_ * 8), dim3(512),
                             args, 0, stream);

  k_final<<<S_ * 4, 256, 0, stream>>>(Hlast, W_out, b_out, out);
}

// Round 17
// 4197.823 us; speedup vs baseline: 1.2825x; 1.2825x over previous
//
#include <hip/hip_runtime.h>
#include <stdint.h>

// ---------------------------------------------------------------------------
// LIDM forward, round 17: REVERT to r13 (proven 4.24 ms). Fragment-major
// shared surfaces + sc0/sc1 bypass + byte-lane flags + deferred noise.
// r15/r16 schedule hoists crashed twice unattributably -> locked to r13.
// ---------------------------------------------------------------------------
#define S_ 256
#define B_ 64
#define O_ 128
#define L_ 256
#define NL_ 25

typedef __attribute__((ext_vector_type(8))) short short8v;
typedef __attribute__((ext_vector_type(16))) float f32x16;
typedef __attribute__((ext_vector_type(4))) uint32_t u32x4;
typedef __attribute__((ext_vector_type(2))) uint32_t u32x2;

// ---- workspace byte offsets ----
#define EMLP_B  0u           // u16 [256][32][64][8]  (fragment-major)
#define HL_B    8388608u     // u16 e1tmp / Hlast [k][fi][b]
#define Z0P_B   16777216u    // u16 [25][32][64][8]
#define RING_B  17596416u    // u16 [25][8][32][64][8]
#define VBUF_B  24150016u    // u16 [25][16][32][64][8]
#define WF_B    37257216u    // u16 [25][1024][256]
#define WN_B    50364416u    // u16 [25][8][32768]
#define BIASF_B 63471616u    // f32 [25][1024]
#define FLAG_B  63574016u    // u64 per layer @ 256B stride
#define NFLAG_B 63580416u    // u16 per (l, p&15) @ 64B stride
#define WS_END  63626016u

// fragment-major panel load: BV[kt] = 16B at base + kt*2048
#define GLDF(BV, BASE)                                                           \
  do {                                                                           \
    uint64_t a0_ = (uint64_t)(uintptr_t)(BASE);                                  \
    uint64_t a1_ = a0_ + 4096,  a2_ = a0_ + 8192,  a3_ = a0_ + 12288;            \
    uint64_t a4_ = a0_ + 16384, a5_ = a0_ + 20480, a6_ = a0_ + 24576;            \
    uint64_t a7_ = a0_ + 28672;                                                  \
    asm volatile("global_load_dwordx4 %0, %1, off sc0 sc1"             : "=v"(BV[0])  : "v"(a0_)); \
    asm volatile("global_load_dwordx4 %0, %1, off offset:2048 sc0 sc1" : "=v"(BV[1])  : "v"(a0_)); \
    asm volatile("global_load_dwordx4 %0, %1, off sc0 sc1"             : "=v"(BV[2])  : "v"(a1_)); \
    asm volatile("global_load_dwordx4 %0, %1, off offset:2048 sc0 sc1" : "=v"(BV[3])  : "v"(a1_)); \
    asm volatile("global_load_dwordx4 %0, %1, off sc0 sc1"             : "=v"(BV[4])  : "v"(a2_)); \
    asm volatile("global_load_dwordx4 %0, %1, off offset:2048 sc0 sc1" : "=v"(BV[5])  : "v"(a2_)); \
    asm volatile("global_load_dwordx4 %0, %1, off sc0 sc1"             : "=v"(BV[6])  : "v"(a3_)); \
    asm volatile("global_load_dwordx4 %0, %1, off offset:2048 sc0 sc1" : "=v"(BV[7])  : "v"(a3_)); \
    asm volatile("global_load_dwordx4 %0, %1, off sc0 sc1"             : "=v"(BV[8])  : "v"(a4_)); \
    asm volatile("global_load_dwordx4 %0, %1, off offset:2048 sc0 sc1" : "=v"(BV[9])  : "v"(a4_)); \
    asm volatile("global_load_dwordx4 %0, %1, off sc0 sc1"             : "=v"(BV[10]) : "v"(a5_)); \
    asm volatile("global_load_dwordx4 %0, %1, off offset:2048 sc0 sc1" : "=v"(BV[11]) : "v"(a5_)); \
    asm volatile("global_load_dwordx4 %0, %1, off sc0 sc1"             : "=v"(BV[12]) : "v"(a6_)); \
    asm volatile("global_load_dwordx4 %0, %1, off offset:2048 sc0 sc1" : "=v"(BV[13]) : "v"(a6_)); \
    asm volatile("global_load_dwordx4 %0, %1, off sc0 sc1"             : "=v"(BV[14]) : "v"(a7_)); \
    asm volatile("global_load_dwordx4 %0, %1, off offset:2048 sc0 sc1" : "=v"(BV[15]) : "v"(a7_)); \
  } while (0)

#define VMWAIT                                                                   \
  do {                                                                           \
    asm volatile("s_waitcnt vmcnt(0)" ::: "memory");                             \
    __builtin_amdgcn_sched_barrier(0);                                           \
  } while (0)

#define GST16(PTR, VAL)                                                          \
  do {                                                                           \
    uint64_t a_ = (uint64_t)(uintptr_t)(PTR);                                    \
    asm volatile("global_store_dwordx4 %0, %1, off sc0 sc1" :: "v"(a_), "v"(VAL) : "memory"); \
  } while (0)

#define GST8(PTR, VAL)                                                           \
  do {                                                                           \
    uint64_t a_ = (uint64_t)(uintptr_t)(PTR);                                    \
    asm volatile("global_store_dwordx2 %0, %1, off sc0 sc1" :: "v"(a_), "v"(VAL) : "memory"); \
  } while (0)

#define VMDRAIN asm volatile("s_waitcnt vmcnt(0)" ::: "memory")

// ---------------------------- helpers --------------------------------------
__device__ __forceinline__ uint16_t f2bf(float x) {
  uint32_t u = __float_as_uint(x);
  return (uint16_t)((u + 0x7fffu + ((u >> 16) & 1u)) >> 16);
}
__device__ __forceinline__ float bf2f(uint16_t u) {
  return __uint_as_float(((uint32_t)u) << 16);
}
__device__ __forceinline__ short8v pack8(float4 a, float4 b) {
  short8v w;
  w[0] = (short)f2bf(a.x); w[1] = (short)f2bf(a.y);
  w[2] = (short)f2bf(a.z); w[3] = (short)f2bf(a.w);
  w[4] = (short)f2bf(b.x); w[5] = (short)f2bf(b.y);
  w[6] = (short)f2bf(b.z); w[7] = (short)f2bf(b.w);
  return w;
}

__device__ __forceinline__ uint32_t rotl32(uint32_t v, int r) {
  return (v << r) | (v >> (32 - r));
}

__device__ __forceinline__ void tf2x32(uint32_t k0, uint32_t k1,
                                       uint32_t x0, uint32_t x1,
                                       uint32_t& o0, uint32_t& o1) {
  uint32_t ks2 = k0 ^ k1 ^ 0x1BD11BDAu;
  x0 += k0; x1 += k1;
  x0 += x1; x1 = rotl32(x1, 13); x1 ^= x0;
  x0 += x1; x1 = rotl32(x1, 15); x1 ^= x0;
  x0 += x1; x1 = rotl32(x1, 26); x1 ^= x0;
  x0 += x1; x1 = rotl32(x1,  6); x1 ^= x0;
  x0 += k1; x1 += ks2 + 1u;
  x0 += x1; x1 = rotl32(x1, 17); x1 ^= x0;
  x0 += x1; x1 = rotl32(x1, 29); x1 ^= x0;
  x0 += x1; x1 = rotl32(x1, 16); x1 ^= x0;
  x0 += x1; x1 = rotl32(x1, 24); x1 ^= x0;
  x0 += ks2; x1 += k0 + 2u;
  x0 += x1; x1 = rotl32(x1, 13); x1 ^= x0;
  x0 += x1; x1 = rotl32(x1, 15); x1 ^= x0;
  x0 += x1; x1 = rotl32(x1, 26); x1 ^= x0;
  x0 += x1; x1 = rotl32(x1,  6); x1 ^= x0;
  x0 += k0; x1 += k1 + 3u;
  x0 += x1; x1 = rotl32(x1, 17); x1 ^= x0;
  x0 += x1; x1 = rotl32(x1, 29); x1 ^= x0;
  x0 += x1; x1 = rotl32(x1, 16); x1 ^= x0;
  x0 += x1; x1 = rotl32(x1, 24); x1 ^= x0;
  x0 += k1; x1 += ks2 + 4u;
  x0 += x1; x1 = rotl32(x1, 13); x1 ^= x0;
  x0 += x1; x1 = rotl32(x1, 15); x1 ^= x0;
  x0 += x1; x1 = rotl32(x1, 26); x1 ^= x0;
  x0 += x1; x1 = rotl32(x1,  6); x1 ^= x0;
  o0 = x0 + ks2; o1 = x1 + k0 + 5u;
}

__device__ __forceinline__ void step_keys(int k, uint32_t& kh0, uint32_t& kh1,
                                          uint32_t& kx0, uint32_t& kx1) {
  uint32_t f0, f1;
  tf2x32(0u, 42u, 0u, (uint32_t)k, f0, f1);
  tf2x32(f0, f1, 0u, 0u, kh0, kh1);
  tf2x32(f0, f1, 0u, 1u, kx0, kx1);
}

__device__ __forceinline__ uint32_t rbits(uint32_t key0, uint32_t key1,
                                          uint32_t i) {
  uint32_t b0, b1;
  tf2x32(key0, key1, 0u, i, b0, b1);
  return b0 ^ b1;
}

__device__ __forceinline__ float u32_to_normal(uint32_t bits) {
  const float lo = __uint_as_float(0xBF7FFFFFu);
  float f = __uint_as_float((bits >> 9) | 0x3F800000u) - 1.0f;
  float u = f * 2.0f + lo;
  u = fmaxf(lo, u);
  float x = u;
  float w = -log1pf(-x * x);
  float p;
  if (w < 5.0f) {
    w -= 2.5f;
    p =            2.81022636e-08f;
    p = fmaf(p, w, 3.43273939e-07f);
    p = fmaf(p, w, -3.5233877e-06f);
    p = fmaf(p, w, -4.39150654e-06f);
    p = fmaf(p, w, 0.00021858087f);
    p = fmaf(p, w, -0.00125372503f);
    p = fmaf(p, w, -0.00417768164f);
    p = fmaf(p, w, 0.246640727f);
    p = fmaf(p, w, 1.50140941f);
  } else {
    w = sqrtf(w) - 3.0f;
    p =            -0.000200214257f;
    p = fmaf(p, w, 0.000100950558f);
    p = fmaf(p, w, 0.00134934322f);
    p = fmaf(p, w, -0.00367342844f);
    p = fmaf(p, w, 0.00573950773f);
    p = fmaf(p, w, -0.0076224613f);
    p = fmaf(p, w, 0.00943887047f);
    p = fmaf(p, w, 1.00167406f);
    p = fmaf(p, w, 2.83297682f);
  }
  return __uint_as_float(0x3FB504F3u) * (p * x);
}

__device__ __forceinline__ float sigm(float x) { return 1.0f / (1.0f + expf(-x)); }

// ---- flag primitives ----
__device__ __forceinline__ uint64_t ld_u64_sc(const uint64_t* p) {
  uint64_t v;
  asm volatile("global_load_dwordx2 %0, %1, off sc0 sc1\n\ts_waitcnt vmcnt(0)"
               : "=v"(v) : "v"((uint64_t)(uintptr_t)p) : "memory");
  return v;
}
__device__ __forceinline__ uint32_t ld_u16_sc(const uint16_t* p) {
  uint32_t v;
  asm volatile("global_load_ushort %0, %1, off sc0 sc1\n\ts_waitcnt vmcnt(0)"
               : "=v"(v) : "v"((uint64_t)(uintptr_t)p) : "memory");
  return v;
}
__device__ __forceinline__ void spin_bytes_ge(const uint64_t* p, uint32_t want) {
  for (;;) {
    uint64_t v = ld_u64_sc(p);
    bool ok = true;
#pragma unroll
    for (int i = 0; i < 8; ++i) ok &= (uint32_t)((v >> (8 * i)) & 0xffu) >= want;
    if (ok) return;
    __builtin_amdgcn_s_sleep(4);
  }
}
__device__ __forceinline__ void spin_nf(const uint16_t* p, uint32_t pid) {
  uint32_t want = (pid & 0xffu) | ((pid & 0xffu) << 8);
  while (ld_u16_sc(p) != want) __builtin_amdgcn_s_sleep(4);
}
__device__ __forceinline__ void st_u8_sc(uint8_t* p, uint32_t v) {
  asm volatile("global_store_byte %0, %1, off sc0 sc1"
               :: "v"((uint64_t)(uintptr_t)p), "v"(v) : "memory");
}

// quarter-panel noise generator (fragment-major vbuf)
__device__ __forceinline__ void gen_quarter(uint16_t* __restrict__ vbl,
                                            int l, int p, int s, int t, int q) {
  uint32_t kh0, kh1, kx0, kx1;
  step_keys(p, kh0, kh1, kx0, kx1);
  int vb = 32 * (s & 1) + (t >> 4);
  int fs = (t & 15) * 16 + q * 4;
  uint32_t ib = ((uint32_t)(l * 64 + vb)) * 256 + (uint32_t)fs;
  int g = fs >> 3;
  uint16_t* dst = vbl + (((size_t)(p & 15)) << 14) + ((size_t)(g * 64 + vb)) * 8 + (fs & 7);
  uint16_t n0 = f2bf(0.1f * u32_to_normal(rbits(kh0, kh1, ib + 0)));
  uint16_t n1 = f2bf(0.1f * u32_to_normal(rbits(kh0, kh1, ib + 1)));
  uint16_t n2 = f2bf(0.1f * u32_to_normal(rbits(kh0, kh1, ib + 2)));
  uint16_t n3 = f2bf(0.1f * u32_to_normal(rbits(kh0, kh1, ib + 3)));
  u32x2 dv;
  dv[0] = (uint32_t)n0 | ((uint32_t)n1 << 16);
  dv[1] = (uint32_t)n2 | ((uint32_t)n3 << 16);
  GST8(dst, dv);
}

// ------------------------------- prep kernels ------------------------------
__global__ __launch_bounds__(256) void k_init(const float* __restrict__ z0,
                                              uint16_t* __restrict__ z0p,
                                              uint32_t* __restrict__ fl) {
  int idx = blockIdx.x * 256 + threadIdx.x;
  int fi = idx & 255;
  int b = (idx >> 8) & 63;
  int l = idx >> 14;
  z0p[(((size_t)l * 32 + (fi >> 3)) * 64 + b) * 8 + (fi & 7)] = f2bf(z0[idx]);
  if (idx < 8000) fl[idx] = 0u;
}

__global__ __launch_bounds__(256) void k_wf(const float* __restrict__ Whh,
                                            const float* __restrict__ Wemb,
                                            uint16_t* __restrict__ Wf) {
  __shared__ float Bs[32][256];
  int l = blockIdx.x >> 4, rt = blockIdx.x & 15;
  int j = threadIdx.x;
  float acc[64];
#pragma unroll
  for (int r = 0; r < 64; ++r) acc[r] = 0.0f;
  const float* Abase = Whh + ((size_t)l * 1024 + rt * 64) * 256;
  for (int m0 = 0; m0 < 256; m0 += 32) {
    __syncthreads();
    {
      int rr = threadIdx.x >> 3, cseg = threadIdx.x & 7;
      const float* src = Wemb + (size_t)(m0 + rr) * 256 + cseg * 32;
      float* dst = &Bs[rr][cseg * 32];
#pragma unroll
      for (int q = 0; q < 8; ++q)
        reinterpret_cast<float4*>(dst)[q] = reinterpret_cast<const float4*>(src)[q];
    }
    __syncthreads();
    for (int mm = 0; mm < 32; ++mm) {
      float bj = Bs[mm][j];
      const float* Acol = Abase + m0 + mm;
#pragma unroll
      for (int r = 0; r < 64; ++r) acc[r] = fmaf(Acol[r * 256], bj, acc[r]);
    }
  }
  for (int r = 0; r < 64; ++r)
    Wf[((size_t)l * 1024 + rt * 64 + r) * 256 + j] = f2bf(acc[r]);
}

__global__ __launch_bounds__(256) void k_wn(const float* __restrict__ Whh,
                                            uint16_t* __restrict__ Wn) {
  int l = blockIdx.x >> 3, s = blockIdx.x & 7;
  uint16_t* base = Wn + ((size_t)(l * 8 + s) << 15);
  for (int it = 0; it < 16; ++it) {
    int c = it * 256 + threadIdx.x;
    int c2 = c >> 7;
    int r = c & 127;
    int gi = (r & 3) * 256 + s * 32 + (r >> 5) * 8 + ((r >> 2) & 7);
    const float* src = Whh + ((size_t)l * 1024 + gi) * 256 + c2 * 8;
    float4 f0 = *reinterpret_cast<const float4*>(src);
    float4 f1 = *reinterpret_cast<const float4*>(src + 4);
    *reinterpret_cast<short8v*>(base + (size_t)c * 8) = pack8(f0, f1);
  }
}

__global__ __launch_bounds__(256) void k_biasf(const float* __restrict__ Whh,
                                               const float* __restrict__ bemb,
                                               const float* __restrict__ bih,
                                               const float* __restrict__ bhh,
                                               float* __restrict__ biasf) {
  int l = blockIdx.x >> 2;
  int gi = (blockIdx.x & 3) * 256 + threadIdx.x;
  const float* row = Whh + ((size_t)l * 1024 + gi) * 256;
  float a = 0.0f;
  for (int m = 0; m < 256; ++m) a = fmaf(row[m], bemb[m], a);
  biasf[l * 1024 + gi] = a + bih[l * 1024 + gi] + bhh[l * 1024 + gi];
}

__global__ __launch_bounds__(256) void k_mlp1(const float* __restrict__ obsrv,
                                              const float* __restrict__ Wx1,
                                              const float* __restrict__ bx1,
                                              uint16_t* __restrict__ e1out) {
  int k = 1 + (blockIdx.x >> 2);
  int jc = blockIdx.x & 3;
  int lane = threadIdx.x & 63;
  int wv = threadIdx.x >> 6;
  int j0 = jc * 64 + wv * 16;
  const float* xrow = obsrv + ((size_t)k * B_ + lane) * O_;
  float acc[16];
#pragma unroll
  for (int i = 0; i < 16; ++i) acc[i] = 0.0f;
  for (int o = 0; o < O_; o += 4) {
    float4 a = *reinterpret_cast<const float4*>(&xrow[o]);
#pragma unroll
    for (int mi = 0; mi < 16; ++mi) {
      float4 wt = *reinterpret_cast<const float4*>(&Wx1[(size_t)(j0 + mi) * O_ + o]);
      float t = acc[mi];
      t = fmaf(a.x, wt.x, t); t = fmaf(a.y, wt.y, t);
      t = fmaf(a.z, wt.z, t); t = fmaf(a.w, wt.w, t);
      acc[mi] = t;
    }
  }
  uint16_t* dst = e1out + (size_t)k * L_ * B_;
#pragma unroll
  for (int mi = 0; mi < 16; ++mi) {
    float v = acc[mi] + bx1[j0 + mi];
    dst[(j0 + mi) * B_ + lane] = f2bf(fmaxf(v, 0.0f));
  }
}

// E_mlp fragment-major: [k][fi>>3][b][fi&7]
__global__ __launch_bounds__(256) void k_mlp2(const uint16_t* __restrict__ e1buf,
                                              const float* __restrict__ Wx2,
                                              const float* __restrict__ bx2,
                                              const float* __restrict__ Wx3,
                                              const float* __restrict__ bx3,
                                              uint16_t* __restrict__ E_mlp) {
  __shared__ float e2s[L_ * B_];
  int k = 1 + blockIdx.x;
  int lane = threadIdx.x & 63;
  int wv = threadIdx.x >> 6;
  const uint16_t* e1 = e1buf + (size_t)k * L_ * B_;

  for (int rep = 0; rep < 4; ++rep) {
    int m0 = rep * 64 + wv * 16;
    float acc[16];
#pragma unroll
    for (int i = 0; i < 16; ++i) acc[i] = 0.0f;
    for (int j = 0; j < L_; j += 4) {
      float a0 = bf2f(e1[(j + 0) * B_ + lane]);
      float a1 = bf2f(e1[(j + 1) * B_ + lane]);
      float a2 = bf2f(e1[(j + 2) * B_ + lane]);
      float a3 = bf2f(e1[(j + 3) * B_ + lane]);
#pragma unroll
      for (int mi = 0; mi < 16; ++mi) {
        float4 wt = *reinterpret_cast<const float4*>(&Wx2[(size_t)(m0 + mi) * L_ + j]);
        float t = acc[mi];
        t = fmaf(a0, wt.x, t); t = fmaf(a1, wt.y, t);
        t = fmaf(a2, wt.z, t); t = fmaf(a3, wt.w, t);
        acc[mi] = t;
      }
    }
#pragma unroll
    for (int mi = 0; mi < 16; ++mi) {
      float v = acc[mi] + bx2[m0 + mi];
      e2s[(m0 + mi) * B_ + lane] = fmaxf(v, 0.0f);
    }
  }
  __syncthreads();

  uint32_t kh0, kh1, kx0, kx1;
  step_keys(k, kh0, kh1, kx0, kx1);
  const float sa = sqrtf(0.9f);

  for (int rep = 0; rep < 4; ++rep) {
    int m0 = rep * 64 + wv * 16;
    float acc[16];
#pragma unroll
    for (int i = 0; i < 16; ++i) acc[i] = 0.0f;
    for (int j = 0; j < L_; j += 4) {
      float a0 = e2s[(j + 0) * B_ + lane];
      float a1 = e2s[(j + 1) * B_ + lane];
      float a2 = e2s[(j + 2) * B_ + lane];
      float a3 = e2s[(j + 3) * B_ + lane];
#pragma unroll
      for (int mi = 0; mi < 16; ++mi) {
        float4 wt = *reinterpret_cast<const float4*>(&Wx3[(size_t)(m0 + mi) * L_ + j]);
        float t = acc[mi];
        t = fmaf(a0, wt.x, t); t = fmaf(a1, wt.y, t);
        t = fmaf(a2, wt.z, t); t = fmaf(a3, wt.w, t);
        acc[mi] = t;
      }
    }
    uint16_t tmp[16];
#pragma unroll
    for (int mi = 0; mi < 16; ++mi) {
      int m = m0 + mi;
      float nz = u32_to_normal(rbits(kx0, kx1, (uint32_t)(lane * L_ + m)));
      tmp[mi] = f2bf(sa * (acc[mi] + bx3[m]) + 0.1f * nz);
    }
    int g0 = m0 >> 3;
    uint16_t* d0 = E_mlp + (((size_t)k * 32 + g0) * 64 + lane) * 8;
    uint16_t* d1 = E_mlp + (((size_t)k * 32 + g0 + 1) * 64 + lane) * 8;
    *reinterpret_cast<uint4*>(d0) = *reinterpret_cast<const uint4*>(&tmp[0]);
    *reinterpret_cast<uint4*>(d1) = *reinterpret_cast<const uint4*>(&tmp[8]);
  }
}

// ------------------------------ wavefront ----------------------------------
__global__ __launch_bounds__(512, 1) void k_wave(
    const uint16_t* __restrict__ Wf, const float* __restrict__ W_ih,
    const uint16_t* __restrict__ Wn, const float* __restrict__ biasf,
    const uint16_t* __restrict__ z0p, const uint16_t* __restrict__ emlp,
    uint16_t* __restrict__ ring, uint16_t* __restrict__ vbuf,
    uint16_t* __restrict__ hlast, uint8_t* __restrict__ flagb,
    uint8_t* __restrict__ nfb) {
  __shared__ __align__(16) unsigned char WAF[65536];
  __shared__ __align__(16) unsigned char WAI[65536];

  const int slot = (blockIdx.x & 7) * 25 + (blockIdx.x >> 3);
  const int l = slot >> 3;
  const int s = slot & 7;
  const int t = threadIdx.x;
  const int lane = t & 63;
  const int wid = t >> 6;
  const int lo5 = lane & 31;
  const int hi = lane >> 5;
  const int tm = wid >> 1;
  const int tn = wid & 1;
  const int bcol = tn * 32 + lo5;
  const int arow = tm * 32 + lo5;
  const int aswz = (arow & 7) << 4;

#pragma unroll 1
  for (int it = 0; it < 8; ++it) {
    int c = it * 512 + t;
    int r = c >> 5, cc = c & 31;
    int gi = (r & 3) * 256 + s * 32 + (r >> 5) * 8 + ((r >> 2) & 7);
    uint4 v = *reinterpret_cast<const uint4*>(Wf + ((size_t)l * 1024 + gi) * 256 + cc * 8);
    *reinterpret_cast<uint4*>(WAF + r * 512 + ((cc * 16) ^ ((r & 7) << 4))) = v;
  }
#pragma unroll 1
  for (int it = 0; it < 8; ++it) {
    int c = it * 512 + t;
    int r = c >> 5, cc = c & 31;
    int gi = (r & 3) * 256 + s * 32 + (r >> 5) * 8 + ((r >> 2) & 7);
    const float* sr = W_ih + ((size_t)l * 1024 + gi) * 256 + cc * 8;
    float4 f0 = *reinterpret_cast<const float4*>(sr);
    float4 f1 = *reinterpret_cast<const float4*>(sr + 4);
    *reinterpret_cast<short8v*>(WAI + r * 512 + ((cc * 16) ^ ((r & 7) << 4))) = pack8(f0, f1);
  }

  float bfr[16];
#pragma unroll
  for (int mq = 0; mq < 4; ++mq) {
    int mi = s * 32 + tm * 8 + mq * 2 + hi;
#pragma unroll
    for (int g = 0; g < 4; ++g)
      bfr[mq * 4 + g] = biasf[l * 1024 + g * 256 + mi];
  }
  __syncthreads();

  uint16_t* vbl = vbuf + ((size_t)(l * 16) << 14);
  const uint16_t* wb = Wn + ((size_t)(l * 8 + s) << 15);
  const int blane = hi * 1024 + bcol * 16;   // fragment-major lane byte offset
  const int ggrp = s * 4 + tm;               // producer fragment group

#define NFE(P) ((uint16_t*)(nfb + ((size_t)(l * 16 + ((P) & 15))) * 64))

  // ---- prologue: generate noise panels 1..8 ----
#pragma unroll 1
  for (int g = 0; g < 2; ++g) {
    int p = 1 + g * 4 + (s >> 1);
#pragma unroll 1
    for (int q = 0; q < 4; ++q) gen_quarter(vbl, l, p, s, t, q);
    VMDRAIN;
    __syncthreads();
    if (t == 0) st_u8_sc((uint8_t*)NFE(p) + (s & 1), (uint32_t)(p & 0xff));
  }

  f32x16 nbt[4];
  float cst[4] = {0.0f, 0.0f, 0.0f, 0.0f};

#define PRO_NBT(ST, IDX)                                                         \
  do {                                                                           \
    if (t == 0) spin_nf(NFE(ST), (uint32_t)(ST));                                \
    __syncthreads();                                                             \
    const unsigned char* V = (const unsigned char*)vbl +                         \
        (((size_t)((ST) & 15)) << 15) + blane;                                   \
    short8v bv[16];                                                              \
    GLDF(bv, V);                                                                 \
    VMWAIT;                                                                      \
    f32x16 nw = {0,0,0,0,0,0,0,0,0,0,0,0,0,0,0,0};                               \
    _Pragma("unroll")                                                            \
    for (int kt = 0; kt < 16; ++kt) {                                            \
      short8v av = *reinterpret_cast<const short8v*>(                            \
          wb + ((size_t)((kt * 2 + hi) * 128 + arow)) * 8);                      \
      nw = __builtin_amdgcn_mfma_f32_32x32x16_bf16(av, bv[kt], nw, 0, 0, 0);     \
    }                                                                            \
    nbt[IDX] = nw;                                                               \
  } while (0)

  PRO_NBT(1, 0);
  PRO_NBT(2, 1);
  PRO_NBT(3, 2);
  PRO_NBT(4, 3);

#pragma unroll 1
  for (int k = 1; k <= 255; ++k) {
    // ---- phase 1: sibling flag (k-1) + downstream ring guard (k-8) ----
    if (t == 0 && k > 1) spin_bytes_ge((const uint64_t*)(flagb + l * 256), (uint32_t)(k - 1));
    if (t == 64 && l < NL_ - 1 && k >= 9)
      spin_bytes_ge((const uint64_t*)(flagb + (l + 1) * 256), (uint32_t)(k - 8));
    __syncthreads();

    // ---- issue hp loads (overlap upstream spin) ----
    const unsigned char* hp = (k == 1)
        ? ((const unsigned char*)z0p + (((size_t)l) << 15) + blane)
        : ((const unsigned char*)ring + (((size_t)(l * 8 + ((k - 1) & 7))) << 15) + blane);
    short8v bv0[16];
    GLDF(bv0, hp);

    // ---- phase 2: upstream flag (k) ----
    if (t == 0 && l > 0) spin_bytes_ge((const uint64_t*)(flagb + (l - 1) * 256), (uint32_t)k);
    __syncthreads();
    VMWAIT;  // bv0 valid

    const unsigned char* ip = (l == 0)
        ? ((const unsigned char*)emlp + (((size_t)k) << 15) + blane)
        : ((const unsigned char*)ring + (((size_t)((l - 1) * 8 + (k & 7))) << 15) + blane);
    short8v bv1[16];
    GLDF(bv1, ip);

    f32x16 acc = nbt[0];
#pragma unroll
    for (int kt = 0; kt < 16; ++kt) {
      short8v av = *reinterpret_cast<const short8v*>(WAF + arow * 512 + ((kt * 32 + hi * 16) ^ aswz));
      acc = __builtin_amdgcn_mfma_f32_32x32x16_bf16(av, bv0[kt], acc, 0, 0, 0);
    }
    VMWAIT;  // bv1 valid
#pragma unroll
    for (int kt = 0; kt < 16; ++kt) {
      short8v av = *reinterpret_cast<const short8v*>(WAI + arow * 512 + ((kt * 32 + hi * 16) ^ aswz));
      acc = __builtin_amdgcn_mfma_f32_32x32x16_bf16(av, bv1[kt], acc, 0, 0, 0);
    }

    // ---- LSTM epilogue ----
    uint16_t hv[4];
#pragma unroll
    for (int mq = 0; mq < 4; ++mq) {
      float iv = acc[4 * mq + 0] + bfr[mq * 4 + 0];
      float fv = acc[4 * mq + 1] + bfr[mq * 4 + 1];
      float gv = acc[4 * mq + 2] + bfr[mq * 4 + 2];
      float ov = acc[4 * mq + 3] + bfr[mq * 4 + 3];
      float cn = sigm(fv) * cst[mq] + sigm(iv) * tanhf(gv);
      float hn = sigm(ov) * tanhf(cn);
      cst[mq] = cn;
      hv[mq] = f2bf(hn);
      if (l == NL_ - 1) {
        int mi = s * 32 + tm * 8 + mq * 2 + hi;
        hlast[((size_t)k << 14) + mi * 64 + bcol] = hv[mq];
      }
    }
    {
      uint32_t w0 = (uint32_t)hv[0] | ((uint32_t)hv[1] << 16);
      uint32_t w1 = (uint32_t)hv[2] | ((uint32_t)hv[3] << 16);
      uint32_t p0 = (uint32_t)__shfl_xor((int)w0, 32);
      uint32_t p1 = (uint32_t)__shfl_xor((int)w1, 32);
      if (hi == 0) {
        u32x4 dv;
        dv[0] = (w0 & 0xffffu) | (p0 << 16);
        dv[1] = (w0 >> 16) | (p0 & 0xffff0000u);
        dv[2] = (w1 & 0xffffu) | (p1 << 16);
        dv[3] = (w1 >> 16) | (p1 & 0xffff0000u);
        // fragment-major: elems 0..7 of (group ggrp, col bcol)
        unsigned char* rp = (unsigned char*)ring +
            (((size_t)(l * 8 + (k & 7))) << 15) + ((size_t)(ggrp * 64 + bcol)) * 16;
        GST16(rp, dv);
      }
    }
    VMDRAIN;
    __syncthreads();
    if (t == 0) st_u8_sc(flagb + l * 256 + s, (uint32_t)(k & 0xff));

    // ================= deferred (off critical path) =================
    {
      int base = ((k - 1) & ~3) + 1;
      int q = (k - 1) & 3;
      int p = base + 8 + (s >> 1);
      if (p <= 255) {
        gen_quarter(vbl, l, p, s, t, q);
        if (q == 3) {
          VMDRAIN;
          __syncthreads();
          if (t == 0) st_u8_sc((uint8_t*)NFE(p) + (s & 1), (uint32_t)(p & 0xff));
        }
      }
    }
    {
      int kn = k + 4;
      f32x16 nw = {0,0,0,0,0,0,0,0,0,0,0,0,0,0,0,0};
      if (kn <= 255) {
        if (t == 0) spin_nf(NFE(kn), (uint32_t)kn);
        __syncthreads();
        const unsigned char* V = (const unsigned char*)vbl +
            (((size_t)(kn & 15)) << 15) + blane;
        short8v bv[16];
        GLDF(bv, V);
        VMWAIT;
#pragma unroll
        for (int kt = 0; kt < 16; ++kt) {
          short8v av = *reinterpret_cast<const short8v*>(
              wb + ((size_t)((kt * 2 + hi) * 128 + arow)) * 8);
          nw = __builtin_amdgcn_mfma_f32_32x32x16_bf16(av, bv[kt], nw, 0, 0, 0);
        }
      }
      nbt[0] = nbt[1]; nbt[1] = nbt[2]; nbt[2] = nbt[3]; nbt[3] = nw;
    }
  }
#undef NFE
#undef PRO_NBT
}

// out[k][b][m] = Hlast[k] @ W_out^T + b_out ; out[0] = 0
__global__ __launch_bounds__(256) void k_final(const uint16_t* __restrict__ Hlast,
                                               const float* __restrict__ W_out,
                                               const float* __restrict__ b_out,
                                               float* __restrict__ out) {
  int k = blockIdx.x >> 2;
  int mc = blockIdx.x & 3;
  int lane = threadIdx.x & 63;
  int wv = threadIdx.x >> 6;
  int m0 = mc * 64 + wv * 16;
  float res[16];
  if (k == 0) {
#pragma unroll
    for (int mi = 0; mi < 16; ++mi) res[mi] = 0.0f;
  } else {
    float acc[16];
#pragma unroll
    for (int i = 0; i < 16; ++i) acc[i] = 0.0f;
    const uint16_t* src = Hlast + ((size_t)k << 14);
    for (int j = 0; j < L_; j += 4) {
      float a0 = bf2f(src[(j + 0) * B_ + lane]);
      float a1 = bf2f(src[(j + 1) * B_ + lane]);
      float a2 = bf2f(src[(j + 2) * B_ + lane]);
      float a3 = bf2f(src[(j + 3) * B_ + lane]);
#pragma unroll
      for (int mi = 0; mi < 16; ++mi) {
        float4 wt = *reinterpret_cast<const float4*>(&W_out[(size_t)(m0 + mi) * L_ + j]);
        float t = acc[mi];
        t = fmaf(a0, wt.x, t); t = fmaf(a1, wt.y, t);
        t = fmaf(a2, wt.z, t); t = fmaf(a3, wt.w, t);
        acc[mi] = t;
      }
    }
#pragma unroll
    for (int mi = 0; mi < 16; ++mi) res[mi] = acc[mi] + b_out[m0 + mi];
  }
  float* dst = out + ((size_t)k * B_ + lane) * L_ + m0;
#pragma unroll
  for (int v = 0; v < 4; ++v) {
    float4 t4 = make_float4(res[4 * v], res[4 * v + 1], res[4 * v + 2], res[4 * v + 3]);
    *reinterpret_cast<float4*>(&dst[4 * v]) = t4;
  }
}

// ------------------------------ launcher -----------------------------------
extern "C" void kernel_launch(void* const* d_in, const int* in_sizes, int n_in,
                              void* d_out, int out_size, void* d_ws, size_t ws_size,
                              hipStream_t stream) {
  const float* obsrv = (const float*)d_in[0];
  const float* z0    = (const float*)d_in[1];
  const float* W_emb = (const float*)d_in[2];
  const float* b_emb = (const float*)d_in[3];
  const float* Wx1   = (const float*)d_in[4];
  const float* bx1   = (const float*)d_in[5];
  const float* Wx2   = (const float*)d_in[6];
  const float* bx2   = (const float*)d_in[7];
  const float* Wx3   = (const float*)d_in[8];
  const float* bx3   = (const float*)d_in[9];
  const float* W_ih  = (const float*)d_in[10];
  const float* W_hh  = (const float*)d_in[11];
  const float* b_ih  = (const float*)d_in[12];
  const float* b_hh  = (const float*)d_in[13];
  const float* W_out = (const float*)d_in[14];
  const float* b_out = (const float*)d_in[15];
  float* out = (float*)d_out;
  unsigned char* ws = (unsigned char*)d_ws;

  if (ws_size < (size_t)WS_END) return;

  uint16_t* E_mlp = (uint16_t*)(ws + EMLP_B);
  uint16_t* e1tmp = (uint16_t*)(ws + HL_B);
  uint16_t* Hlast = (uint16_t*)(ws + HL_B);
  uint16_t* z0p   = (uint16_t*)(ws + Z0P_B);
  uint16_t* ring  = (uint16_t*)(ws + RING_B);
  uint16_t* vbuf  = (uint16_t*)(ws + VBUF_B);
  uint16_t* Wf    = (uint16_t*)(ws + WF_B);
  uint16_t* Wn    = (uint16_t*)(ws + WN_B);
  float*    biasf = (float*)(ws + BIASF_B);
  uint8_t*  flagb = (uint8_t*)(ws + FLAG_B);
  uint8_t*  nfb   = (uint8_t*)(ws + NFLAG_B);

  k_init<<<1600, 256, 0, stream>>>(z0, z0p, (uint32_t*)(ws + FLAG_B));
  k_wf<<<25 * 16, 256, 0, stream>>>(W_hh, W_emb, Wf);
  k_wn<<<25 * 8, 256, 0, stream>>>(W_hh, Wn);
  k_biasf<<<25 * 4, 256, 0, stream>>>(W_hh, b_emb, b_ih, b_hh, biasf);
  k_mlp1<<<255 * 4, 256, 0, stream>>>(obsrv, Wx1, bx1, e1tmp);
  k_mlp2<<<255, 256, 0, stream>>>(e1tmp, Wx2, bx2, Wx3, bx3, E_mlp);

  void* args[] = {(void*)&Wf, (void*)&W_ih, (void*)&Wn, (void*)&biasf,
                  (void*)&z0p, (void*)&E_mlp, (void*)&ring, (void*)&vbuf,
                  (void*)&Hlast, (void*)&flagb, (void*)&nfb};
  hipLaunchCooperativeKernel((const void*)k_wave, dim3(NL_ * 8), dim3(512),
                             args, 0, stream);

  k_final<<<S_ * 4, 256, 0, stream>>>(Hlast, W_out, b_out, out);
}